// Round 12
// baseline (3531.137 us; speedup 1.0000x reference)
//
#include <hip/hip_runtime.h>
#include <math.h>

#define B_TOT 2048
#define T_LEN 512
#define HDIM 64
#define FC1 50
#define NSUP2 514   // pair-v2: 512 + skew 2

typedef __bf16 bf16x8 __attribute__((ext_vector_type(8)));
typedef float f32x4 __attribute__((ext_vector_type(4)));
typedef unsigned int u32x4 __attribute__((ext_vector_type(4)));

// Fast transcendentals (no -ffast-math in harness; "/" would emit 12-inst IEEE div)
__device__ __forceinline__ float vrcp(float x) {
  float r; asm("v_rcp_f32 %0, %1" : "=v"(r) : "v"(x)); return r;
}
__device__ __forceinline__ float vexp2(float x) {
  float r; asm("v_exp_f32 %0, %1" : "=v"(r) : "v"(x)); return r;
}
__device__ __forceinline__ float sigm(float x) {
  return vrcp(1.0f + vexp2(x * -1.44269504088896340736f));
}
__device__ __forceinline__ float tanh_(float x) {
  return fmaf(2.0f, vrcp(1.0f + vexp2(x * -2.8853900817779268f)), -1.0f);
}

// lgkm-only barrier: LDS visibility without draining global queues.
#define BARRIER() asm volatile("s_waitcnt lgkmcnt(0)\n\ts_barrier" ::: "memory")
#define MFMA __builtin_amdgcn_mfma_f32_16x16x32_bf16

// Planar [16][64] bf16, 16B-chunk XOR swizzle: full-wave b128 = uniform 8 lanes/bank-group.
#define HADDR(row, chunk) (((row) << 6) + ((((chunk) ^ ((row) & 7))) << 3))

__device__ __forceinline__ void unpk(u32x4 p0, u32x4 p1, bf16x8* hi, bf16x8* lo) {
  u32x4 h, l;
  h[0] = __builtin_amdgcn_perm(p0[1], p0[0], 0x05040100u);
  h[1] = __builtin_amdgcn_perm(p0[3], p0[2], 0x05040100u);
  h[2] = __builtin_amdgcn_perm(p1[1], p1[0], 0x05040100u);
  h[3] = __builtin_amdgcn_perm(p1[3], p1[2], 0x05040100u);
  l[0] = __builtin_amdgcn_perm(p0[1], p0[0], 0x07060302u);
  l[1] = __builtin_amdgcn_perm(p0[3], p0[2], 0x07060302u);
  l[2] = __builtin_amdgcn_perm(p1[1], p1[0], 0x07060302u);
  l[3] = __builtin_amdgcn_perm(p1[3], p1[2], 0x07060302u);
  *hi = __builtin_bit_cast(bf16x8, h);
  *lo = __builtin_bit_cast(bf16x8, l);
}

// A-wave recurrence body (R9-proven chain): 4 planar ds_read_b128 ->
// 4 chained h-MFMAs seeded from accx[S_][P_] -> fp32 gates -> planar ds_write.
#define ABODY(S_, P_)                                                          \
  {                                                                            \
    bf16x8 ahh0 = *(const bf16x8*)&Hhi[S_][1 - (P_)][HADDR(nn, cg)];           \
    bf16x8 ahh1 = *(const bf16x8*)&Hhi[S_][1 - (P_)][HADDR(nn, 4 + cg)];       \
    bf16x8 ahl0 = *(const bf16x8*)&Hlo[S_][1 - (P_)][HADDR(nn, cg)];           \
    bf16x8 ahl1 = *(const bf16x8*)&Hlo[S_][1 - (P_)][HADDR(nn, 4 + cg)];       \
    f32x4 accs[4];                                                             \
    _Pragma("unroll") for (int g = 0; g < 4; ++g) {                            \
      f32x4 a = accx[S_][P_][g][wq * 64 + lane];                               \
      a = MFMA(ahh0, bhh[g][0], a, 0, 0, 0);                                   \
      a = MFMA(ahh1, bhh[g][1], a, 0, 0, 0);                                   \
      a = MFMA(ahl0, bhh[g][0], a, 0, 0, 0);                                   \
      a = MFMA(ahl1, bhh[g][1], a, 0, 0, 0);                                   \
      accs[g] = a;                                                             \
    }                                                                          \
    _Pragma("unroll") for (int r = 0; r < 4; ++r) {                            \
      float iv = sigm(accs[0][r]);                                             \
      float fv = sigm(accs[1][r]);                                             \
      float gv = tanh_(accs[2][r]);                                            \
      float ov = sigm(accs[3][r]);                                             \
      cell[r] = fv * cell[r] + iv * gv;                                        \
      float hv = ov * tanh_(cell[r]);                                          \
      __bf16 h1 = (__bf16)hv;                                                  \
      __bf16 h2 = (__bf16)(hv - (float)h1);                                    \
      int mrow = 4 * cg + r;                                                   \
      int ha = HADDR(mrow, uu >> 3) + (uu & 7);                                \
      Hhi[S_][P_][ha] = h1;                                                    \
      Hlo[S_][P_][ha] = h2;                                                    \
    }                                                                          \
  }

// ---------- Pair kernel v2: 2 layers, each with R9's A/B wave split ----------
// 1024 thr = 16 waves: set = wv>>3 (layer L0+set), sub = wv&7, A = sub<4.
// Schedule (superstep n, parity P=n&1):
//   set0-A: h0(n) from accx0[P] + own planes [0][1-P]; writes planes [0][P].
//   set0-B: accx0[1-P] for t=n+1 from x-queue[P]; refill queue[P] = x(n+3).
//   set1-A: h1(n-2) from accx1[P] + own planes [1][1-P]; writes planes [1][P].
//   set1-B: store h1(n-3) from planes [1][1-P]; accx1[1-P] for t=n-1 from
//           upstream h0(n-1) = planes [0][1-P] (4 x-MFMAs, bias-seeded).
// One lgkm barrier per superstep. Numerics identical to R9/R11 (1.2207e-4).
// In-place (GIN): set0-B reads seq[n+3], set1-B writes seq[n-3] -> gap 6.
#define SUPER(N_, P_)                                                          \
  {                                                                            \
    if (set == 0) {                                                            \
      if (isA) {                                                               \
        if ((N_) < T_LEN) ABODY(0, P_);                                        \
      } else {                                                                 \
        if ((N_) + 1 < T_LEN) {                                                \
          if (XIN) {                                                           \
            _Pragma("unroll") for (int g = 0; g < 4; ++g) {                    \
              f32x4 a;                                                         \
              _Pragma("unroll") for (int r = 0; r < 4; ++r)                    \
                a[r] = bias[g] + xw[g*3+0] * xr[P_][r*3+0]                     \
                               + xw[g*3+1] * xr[P_][r*3+1]                     \
                               + xw[g*3+2] * xr[P_][r*3+2];                    \
              accx[0][1 - (P_)][g][wq * 64 + lane] = a;                        \
            }                                                                  \
          } else {                                                             \
            bf16x8 xh0, xl0, xh1, xl1;                                         \
            unpk(xpk[P_][0], xpk[P_][1], &xh0, &xl0);                          \
            unpk(xpk[P_][2], xpk[P_][3], &xh1, &xl1);                          \
            _Pragma("unroll") for (int g = 0; g < 4; ++g) {                    \
              f32x4 a = {bias[g], bias[g], bias[g], bias[g]};                  \
              a = MFMA(xh0, bih[g][0], a, 0, 0, 0);                            \
              a = MFMA(xh1, bih[g][1], a, 0, 0, 0);                            \
              a = MFMA(xl0, bih[g][0], a, 0, 0, 0);                            \
              a = MFMA(xl1, bih[g][1], a, 0, 0, 0);                            \
              accx[0][1 - (P_)][g][wq * 64 + lane] = a;                        \
            }                                                                  \
          }                                                                    \
        }                                                                      \
        {                                                                      \
          int tp = (N_) + 3; if (tp > T_LEN - 1) tp = T_LEN - 1;               \
          if (XIN) {                                                           \
            _Pragma("unroll") for (int r = 0; r < 4; ++r)                      \
              _Pragma("unroll") for (int i = 0; i < 3; ++i)                    \
                xr[P_][r*3+i] =                                                \
                    x_f32[((size_t)(bbase + 4*cg + r) * T_LEN + tp) * 3 + i];  \
          } else {                                                             \
            const unsigned int* px = seqp + xrow + (size_t)tp * HDIM;          \
            xpk[P_][0] = *(const u32x4*)(px + 8 * cg);                         \
            xpk[P_][1] = *(const u32x4*)(px + 8 * cg + 4);                     \
            xpk[P_][2] = *(const u32x4*)(px + 32 + 8 * cg);                    \
            xpk[P_][3] = *(const u32x4*)(px + 32 + 8 * cg + 4);                \
          }                                                                    \
        }                                                                      \
      }                                                                        \
    } else {                                                                   \
      if (isA) {                                                               \
        if ((N_) >= 2) ABODY(1, P_);   /* t1 = N_-2, <=511 since N_<514 */     \
      } else {                                                                 \
        if ((N_) >= 3) {                                                       \
          _Pragma("unroll") for (int r = 0; r < 4; ++r) {                      \
            int mrow = 4 * cg + r;                                             \
            int ha = HADDR(mrow, uu >> 3) + (uu & 7);                          \
            unsigned int hb =                                                  \
                (unsigned int)__builtin_bit_cast(unsigned short, Hhi[1][1 - (P_)][ha]) \
              | ((unsigned int)__builtin_bit_cast(unsigned short, Hlo[1][1 - (P_)][ha]) << 16); \
            seqp[((size_t)(bbase + mrow) * T_LEN + (N_) - 3) * HDIM + uu] = hb;\
          }                                                                    \
        }                                                                      \
        if ((N_) >= 1 && (N_) <= T_LEN) {                                      \
          bf16x8 xh0 = *(const bf16x8*)&Hhi[0][1 - (P_)][HADDR(nn, cg)];       \
          bf16x8 xh1 = *(const bf16x8*)&Hhi[0][1 - (P_)][HADDR(nn, 4 + cg)];   \
          bf16x8 xl0 = *(const bf16x8*)&Hlo[0][1 - (P_)][HADDR(nn, cg)];       \
          bf16x8 xl1 = *(const bf16x8*)&Hlo[0][1 - (P_)][HADDR(nn, 4 + cg)];   \
          _Pragma("unroll") for (int g = 0; g < 4; ++g) {                      \
            f32x4 a = {bias[g], bias[g], bias[g], bias[g]};                    \
            a = MFMA(xh0, bih[g][0], a, 0, 0, 0);                              \
            a = MFMA(xh1, bih[g][1], a, 0, 0, 0);                              \
            a = MFMA(xl0, bih[g][0], a, 0, 0, 0);                              \
            a = MFMA(xl1, bih[g][1], a, 0, 0, 0);                              \
            accx[1][1 - (P_)][g][wq * 64 + lane] = a;                          \
          }                                                                    \
        }                                                                      \
      }                                                                        \
    }                                                                          \
    BARRIER();                                                                 \
  }

template<int L0, bool XIN>
__global__ __launch_bounds__(1024, 1)
void lstm_pair2(const float* __restrict__ x_f32,
                const float* __restrict__ w_ih0,
                const float* __restrict__ w_ih_rest,
                const float* __restrict__ w_hh,
                const float* __restrict__ b_ih,
                const float* __restrict__ b_hh,
                unsigned int* __restrict__ seqp)
{
  const int tid  = threadIdx.x;
  const int lane = tid & 63;
  const int wv   = tid >> 6;      // 0..15
  const int set  = wv >> 3;       // 0,1 (wave-uniform)
  const int sub  = wv & 7;
  const bool isA = (sub < 4);
  const int wq   = sub & 3;
  const int nn   = lane & 15;
  const int cg   = lane >> 4;
  const int bbase = blockIdx.x * 16;
  const int grow = 16 * wq + nn;
  const int uu   = grow;
  const int layer = L0 + set;

  __shared__ __align__(16) __bf16 Hhi[2][2][1024];        // 8 KB
  __shared__ __align__(16) __bf16 Hlo[2][2][1024];        // 8 KB
  __shared__ __align__(16) f32x4 accx[2][2][4][256];      // 64 KB

  bf16x8 bhh[4][2];   // A-waves
  bf16x8 bih[4][2];   // B-waves (set0 GIN / set1)
  float xw[12];       // B set0 XIN
  float bias[4];      // B-waves
  if (isA) {
#pragma unroll
    for (int g = 0; g < 4; ++g)
#pragma unroll
      for (int kk = 0; kk < 2; ++kk) {
        const float* wp = w_hh + (size_t)layer * 256 * 64
                        + (size_t)(64 * g + grow) * 64 + kk * 32 + 8 * cg;
        bf16x8 t;
#pragma unroll
        for (int e = 0; e < 8; ++e) t[e] = (__bf16)wp[e];
        bhh[g][kk] = t;
      }
  } else {
#pragma unroll
    for (int g = 0; g < 4; ++g) {
      int row = layer * 256 + 64 * g + grow;
      bias[g] = b_ih[row] + b_hh[row];
    }
    if (XIN && set == 0) {
#pragma unroll
      for (int g = 0; g < 4; ++g)
#pragma unroll
        for (int i = 0; i < 3; ++i) xw[g * 3 + i] = w_ih0[(64 * g + grow) * 3 + i];
    } else {
      const float* wih_l = w_ih_rest + (size_t)(layer - 1) * 256 * 64;
#pragma unroll
      for (int g = 0; g < 4; ++g)
#pragma unroll
        for (int kk = 0; kk < 2; ++kk) {
          const float* wp = wih_l + (size_t)(64 * g + grow) * 64 + kk * 32 + 8 * cg;
          bf16x8 t;
#pragma unroll
          for (int e = 0; e < 8; ++e) t[e] = (__bf16)wp[e];
          bih[g][kk] = t;
        }
    }
  }

  for (int q = tid; q < 4 * 1024; q += 1024) {
    ((__bf16*)Hhi)[q] = (__bf16)0.f;
    ((__bf16*)Hlo)[q] = (__bf16)0.f;
  }

  float cell[4] = {0.f, 0.f, 0.f, 0.f};
  const size_t xrow = (size_t)(bbase + nn) * T_LEN * HDIM;

  float xr[2][12];
  u32x4 xpk[2][4];
  if (!isA && set == 0) {
    if (XIN) {
      float x0[12];
#pragma unroll
      for (int r = 0; r < 4; ++r)
#pragma unroll
        for (int i = 0; i < 3; ++i)
          x0[r*3+i] = x_f32[((size_t)(bbase + 4*cg + r) * T_LEN + 0) * 3 + i];
#pragma unroll
      for (int g = 0; g < 4; ++g) {
        f32x4 a;
#pragma unroll
        for (int r = 0; r < 4; ++r)
          a[r] = bias[g] + xw[g*3+0]*x0[r*3+0] + xw[g*3+1]*x0[r*3+1] + xw[g*3+2]*x0[r*3+2];
        accx[0][0][g][wq * 64 + lane] = a;
      }
#pragma unroll
      for (int p = 0; p < 2; ++p)
#pragma unroll
        for (int r = 0; r < 4; ++r)
#pragma unroll
          for (int i = 0; i < 3; ++i)
            xr[p][r*3+i] = x_f32[((size_t)(bbase + 4*cg + r) * T_LEN + (p + 1)) * 3 + i];
    } else {
      const unsigned int* px = seqp + xrow;
      u32x4 q0 = *(const u32x4*)(px + 8 * cg);
      u32x4 q1 = *(const u32x4*)(px + 8 * cg + 4);
      u32x4 q2 = *(const u32x4*)(px + 32 + 8 * cg);
      u32x4 q3 = *(const u32x4*)(px + 32 + 8 * cg + 4);
      bf16x8 xh0, xl0, xh1, xl1;
      unpk(q0, q1, &xh0, &xl0);
      unpk(q2, q3, &xh1, &xl1);
#pragma unroll
      for (int g = 0; g < 4; ++g) {
        f32x4 a = {bias[g], bias[g], bias[g], bias[g]};
        a = MFMA(xh0, bih[g][0], a, 0, 0, 0);
        a = MFMA(xh1, bih[g][1], a, 0, 0, 0);
        a = MFMA(xl0, bih[g][0], a, 0, 0, 0);
        a = MFMA(xl1, bih[g][1], a, 0, 0, 0);
        accx[0][0][g][wq * 64 + lane] = a;
      }
#pragma unroll
      for (int p = 0; p < 2; ++p) {
        const unsigned int* pq = seqp + xrow + (size_t)(p + 1) * HDIM;
        xpk[p][0] = *(const u32x4*)(pq + 8 * cg);
        xpk[p][1] = *(const u32x4*)(pq + 8 * cg + 4);
        xpk[p][2] = *(const u32x4*)(pq + 32 + 8 * cg);
        xpk[p][3] = *(const u32x4*)(pq + 32 + 8 * cg + 4);
      }
    }
  }
  __syncthreads();

  if (isA) __builtin_amdgcn_s_setprio(1);
  for (int n = 0; n < NSUP2; n += 2) {
    SUPER(n,     0);
    SUPER(n + 1, 1);
  }
  if (isA) __builtin_amdgcn_s_setprio(0);

  // tail: store h1(T-1) — computed at superstep 513 into planes [1][1]
  if (!isA && set == 1) {
#pragma unroll
    for (int r = 0; r < 4; ++r) {
      int mrow = 4 * cg + r;
      int ha = HADDR(mrow, uu >> 3) + (uu & 7);
      unsigned int hb =
          (unsigned int)__builtin_bit_cast(unsigned short, Hhi[1][1][ha])
        | ((unsigned int)__builtin_bit_cast(unsigned short, Hlo[1][1][ha]) << 16);
      seqp[((size_t)(bbase + mrow) * T_LEN + (T_LEN - 1)) * HDIM + uu] = hb;
    }
  }
}

// -------------- Single-layer kernel (R9/R11-proven, layer 4) ---------------
#define STEP(T0, P)                                                            \
  {                                                                            \
    if (isA) {                                                                 \
      bf16x8 ahh0 = *(const bf16x8*)&h_hi[P][HADDR(nn, cg)];                   \
      bf16x8 ahh1 = *(const bf16x8*)&h_hi[P][HADDR(nn, 4 + cg)];               \
      bf16x8 ahl0 = *(const bf16x8*)&h_lo[P][HADDR(nn, cg)];                   \
      bf16x8 ahl1 = *(const bf16x8*)&h_lo[P][HADDR(nn, 4 + cg)];               \
      f32x4 accs[4];                                                           \
      _Pragma("unroll")                                                        \
      for (int g = 0; g < 4; ++g) {                                            \
        f32x4 a = accx[P][g][wq * 64 + lane];                                  \
        a = MFMA(ahh0, bhh[g][0], a, 0, 0, 0);                                 \
        a = MFMA(ahh1, bhh[g][1], a, 0, 0, 0);                                 \
        a = MFMA(ahl0, bhh[g][0], a, 0, 0, 0);                                 \
        a = MFMA(ahl1, bhh[g][1], a, 0, 0, 0);                                 \
        accs[g] = a;                                                           \
      }                                                                        \
      _Pragma("unroll")                                                        \
      for (int r = 0; r < 4; ++r) {                                            \
        float iv = sigm(accs[0][r]);                                           \
        float fv = sigm(accs[1][r]);                                           \
        float gv = tanh_(accs[2][r]);                                          \
        float ov = sigm(accs[3][r]);                                           \
        cell[r] = fv * cell[r] + iv * gv;                                      \
        float hv = ov * tanh_(cell[r]);                                        \
        __bf16 h1 = (__bf16)hv;                                                \
        __bf16 h2 = (__bf16)(hv - (float)h1);                                  \
        int mrow = 4 * cg + r;                                                 \
        int ha = HADDR(mrow, uu >> 3) + (uu & 7);                              \
        h_hi[1 - (P)][ha] = h1;                                                \
        h_lo[1 - (P)][ha] = h2;                                                \
      }                                                                        \
    } else {                                                                   \
      if ((T0) > 0) {                                                          \
        _Pragma("unroll")                                                      \
        for (int r = 0; r < 4; ++r) {                                          \
          int mrow = 4 * cg + r;                                               \
          int ha = HADDR(mrow, uu >> 3) + (uu & 7);                            \
          unsigned int hb =                                                    \
              (unsigned int)__builtin_bit_cast(unsigned short, h_hi[P][ha])    \
            | ((unsigned int)__builtin_bit_cast(unsigned short, h_lo[P][ha]) << 16); \
          seqp[((size_t)(bbase + mrow) * T_LEN + (T0) - 1) * HDIM + uu] = hb;  \
        }                                                                      \
      }                                                                        \
      if ((T0) + 1 < T_LEN) {                                                  \
        bf16x8 xh0, xl0, xh1, xl1;                                             \
        unpk(xpk[P][0], xpk[P][1], &xh0, &xl0);                                \
        unpk(xpk[P][2], xpk[P][3], &xh1, &xl1);                                \
        _Pragma("unroll")                                                      \
        for (int g = 0; g < 4; ++g) {                                          \
          f32x4 a = {bias[g], bias[g], bias[g], bias[g]};                      \
          a = MFMA(xh0, bih[g][0], a, 0, 0, 0);                                \
          a = MFMA(xh1, bih[g][1], a, 0, 0, 0);                                \
          a = MFMA(xl0, bih[g][0], a, 0, 0, 0);                                \
          a = MFMA(xl1, bih[g][1], a, 0, 0, 0);                                \
          accx[1 - (P)][g][wq * 64 + lane] = a;                                \
        }                                                                      \
      }                                                                        \
      {                                                                        \
        int tp = (T0) + 3; if (tp >= T_LEN) tp = T_LEN - 1;                    \
        const unsigned int* px = seqp + xrow + (size_t)tp * HDIM;              \
        xpk[P][0] = *(const u32x4*)(px + 8 * cg);                              \
        xpk[P][1] = *(const u32x4*)(px + 8 * cg + 4);                          \
        xpk[P][2] = *(const u32x4*)(px + 32 + 8 * cg);                         \
        xpk[P][3] = *(const u32x4*)(px + 32 + 8 * cg + 4);                     \
      }                                                                        \
    }                                                                          \
    BARRIER();                                                                 \
  }

__global__ __launch_bounds__(512, 2)
void lstm_single(const float* __restrict__ w_ih,
                 const float* __restrict__ w_hh,
                 const float* __restrict__ b_ih,
                 const float* __restrict__ b_hh,
                 unsigned int* seqp)
{
    const int tid  = threadIdx.x;
    const int lane = tid & 63;
    const int wv   = tid >> 6;
    const bool isA = (wv < 4);
    const int wq   = wv & 3;
    const int nn   = lane & 15;
    const int cg   = lane >> 4;
    const int bbase = blockIdx.x * 16;
    const int grow = 16 * wq + nn;
    const int uu   = grow;

    __shared__ __align__(16) __bf16 h_hi[2][16 * 64];
    __shared__ __align__(16) __bf16 h_lo[2][16 * 64];
    __shared__ __align__(16) f32x4 accx[2][4][256];

    bf16x8 bhh[4][2];
    bf16x8 bih[4][2];
    float bias[4];
    if (isA) {
#pragma unroll
      for (int g = 0; g < 4; ++g)
#pragma unroll
        for (int kk = 0; kk < 2; ++kk) {
          const float* wp = w_hh + (size_t)(64 * g + grow) * 64 + kk * 32 + 8 * cg;
          bf16x8 t;
#pragma unroll
          for (int e = 0; e < 8; ++e) t[e] = (__bf16)wp[e];
          bhh[g][kk] = t;
        }
    } else {
#pragma unroll
      for (int g = 0; g < 4; ++g) {
        int row = 64 * g + grow;
        bias[g] = b_ih[row] + b_hh[row];
      }
#pragma unroll
      for (int g = 0; g < 4; ++g)
#pragma unroll
        for (int kk = 0; kk < 2; ++kk) {
          const float* wp = w_ih + (size_t)(64 * g + grow) * 64 + kk * 32 + 8 * cg;
          bf16x8 t;
#pragma unroll
          for (int e = 0; e < 8; ++e) t[e] = (__bf16)wp[e];
          bih[g][kk] = t;
        }
    }

    for (int q = tid; q < 1024; q += 512) {
      h_hi[0][q] = (__bf16)0.f; h_hi[1][q] = (__bf16)0.f;
      h_lo[0][q] = (__bf16)0.f; h_lo[1][q] = (__bf16)0.f;
    }

    float cell[4] = {0.f, 0.f, 0.f, 0.f};
    const size_t xrow = (size_t)(bbase + nn) * T_LEN * HDIM;
    u32x4 xpk[2][4];

    if (!isA) {
      const unsigned int* px = seqp + xrow;
      u32x4 q0 = *(const u32x4*)(px + 8 * cg);
      u32x4 q1 = *(const u32x4*)(px + 8 * cg + 4);
      u32x4 q2 = *(const u32x4*)(px + 32 + 8 * cg);
      u32x4 q3 = *(const u32x4*)(px + 32 + 8 * cg + 4);
      bf16x8 xh0, xl0, xh1, xl1;
      unpk(q0, q1, &xh0, &xl0);
      unpk(q2, q3, &xh1, &xl1);
#pragma unroll
      for (int g = 0; g < 4; ++g) {
        f32x4 a = {bias[g], bias[g], bias[g], bias[g]};
        a = MFMA(xh0, bih[g][0], a, 0, 0, 0);
        a = MFMA(xh1, bih[g][1], a, 0, 0, 0);
        a = MFMA(xl0, bih[g][0], a, 0, 0, 0);
        a = MFMA(xl1, bih[g][1], a, 0, 0, 0);
        accx[0][g][wq * 64 + lane] = a;
      }
#pragma unroll
      for (int p = 0; p < 2; ++p) {
        const unsigned int* pq = seqp + xrow + (size_t)(p + 1) * HDIM;
        xpk[p][0] = *(const u32x4*)(pq + 8 * cg);
        xpk[p][1] = *(const u32x4*)(pq + 8 * cg + 4);
        xpk[p][2] = *(const u32x4*)(pq + 32 + 8 * cg);
        xpk[p][3] = *(const u32x4*)(pq + 32 + 8 * cg + 4);
      }
    }
    __syncthreads();

    if (isA) __builtin_amdgcn_s_setprio(1);
    for (int t = 0; t < T_LEN; t += 2) {
      STEP(t, 0);
      STEP(t + 1, 1);
    }
    if (isA) __builtin_amdgcn_s_setprio(0);

    if (!isA) {
#pragma unroll
      for (int r = 0; r < 4; ++r) {
        int mrow = 4 * cg + r;
        int ha = HADDR(mrow, uu >> 3) + (uu & 7);
        unsigned int hb =
            (unsigned int)__builtin_bit_cast(unsigned short, h_hi[0][ha])
          | ((unsigned int)__builtin_bit_cast(unsigned short, h_lo[0][ha]) << 16);
        seqp[((size_t)(bbase + mrow) * T_LEN + (T_LEN - 1)) * HDIM + uu] = hb;
      }
    }
}

// FC head: out[b] = fc2_b + fc2_w . relu(fc1_b + fc1_w . h_T[b])
__global__ __launch_bounds__(256, 1)
void fc_head(const unsigned int* __restrict__ seqp,
             const float* __restrict__ fc1_w, const float* __restrict__ fc1_b,
             const float* __restrict__ fc2_w, const float* __restrict__ fc2_b,
             float* __restrict__ out)
{
    __shared__ float w1[FC1 * HDIM];
    __shared__ float b1[FC1];
    __shared__ float w2[FC1];
    const int tid = threadIdx.x;
    for (int i = tid; i < FC1 * HDIM; i += 256) w1[i] = fc1_w[i];
    if (tid < FC1) { b1[tid] = fc1_b[tid]; w2[tid] = fc2_w[tid]; }
    __syncthreads();

    const int b = blockIdx.x * 256 + tid;
    const size_t base = ((size_t)b * T_LEN + (T_LEN - 1)) * HDIM;
    float h[HDIM];
#pragma unroll
    for (int q = 0; q < HDIM; ++q) {
      unsigned int v = seqp[base + q];
      float hi = (float)__builtin_bit_cast(__bf16, (unsigned short)(v & 0xffffu));
      float lo = (float)__builtin_bit_cast(__bf16, (unsigned short)(v >> 16));
      h[q] = hi + lo;
    }
    float acc2 = fc2_b[0];
    for (int m = 0; m < FC1; ++m) {
      float a = b1[m];
#pragma unroll
      for (int q = 0; q < HDIM; ++q) a += w1[m * HDIM + q] * h[q];
      acc2 += w2[m] * fmaxf(a, 0.0f);
    }
    out[b] = acc2;
}

extern "C" void kernel_launch(void* const* d_in, const int* in_sizes, int n_in,
                              void* d_out, int out_size, void* d_ws, size_t ws_size,
                              hipStream_t stream) {
    const float* x         = (const float*)d_in[0];
    const float* w_ih0     = (const float*)d_in[1];
    const float* w_ih_rest = (const float*)d_in[2];
    const float* w_hh      = (const float*)d_in[3];
    const float* b_ih      = (const float*)d_in[4];
    const float* b_hh      = (const float*)d_in[5];
    const float* fc1_w     = (const float*)d_in[6];
    const float* fc1_b     = (const float*)d_in[7];
    const float* fc2_w     = (const float*)d_in[8];
    const float* fc2_b     = (const float*)d_in[9];
    float* out = (float*)d_out;

    unsigned int* seqp = (unsigned int*)d_ws;   // [B,T,64] packed = 256 MiB

    // layers 0+1 (A/B split per set); writes seq1
    lstm_pair2<0, true><<<dim3(B_TOT / 16), dim3(1024), 0, stream>>>(
        x, w_ih0, w_ih_rest, w_hh, b_ih, b_hh, seqp);
    // layers 2+3; reads seq1 / writes seq3 in-place (gap 6)
    lstm_pair2<2, false><<<dim3(B_TOT / 16), dim3(1024), 0, stream>>>(
        x, w_ih0, w_ih_rest, w_hh, b_ih, b_hh, seqp);
    // layer 4; reads seq3 / writes seq4 in-place (gap 4)
    lstm_single<<<dim3(B_TOT / 16), dim3(512), 0, stream>>>(
        w_ih_rest + (size_t)3 * 256 * HDIM,
        w_hh + (size_t)4 * 256 * HDIM,
        b_ih + (size_t)4 * 256,
        b_hh + (size_t)4 * 256,
        seqp);
    fc_head<<<dim3(B_TOT / 256), dim3(256), 0, stream>>>(
        seqp, fc1_w, fc1_b, fc2_w, fc2_b, out);
}

// Round 13
// 1578.413 us; speedup vs baseline: 2.2371x; 2.2371x over previous
//
#include <hip/hip_runtime.h>
#include <math.h>

#define B_TOT 2048
#define T_LEN 512
#define HDIM 64
#define FC1 50
#define NSUP 514   // skew-2 pair: 512 + 2

typedef __bf16 bf16x8 __attribute__((ext_vector_type(8)));
typedef float f32x4 __attribute__((ext_vector_type(4)));
typedef unsigned int u32x4 __attribute__((ext_vector_type(4)));

// Fast transcendentals (no -ffast-math in harness; "/" would emit 12-inst IEEE div)
__device__ __forceinline__ float vrcp(float x) {
  float r; asm("v_rcp_f32 %0, %1" : "=v"(r) : "v"(x)); return r;
}
__device__ __forceinline__ float vexp2(float x) {
  float r; asm("v_exp_f32 %0, %1" : "=v"(r) : "v"(x)); return r;
}
__device__ __forceinline__ float sigm(float x) {
  return vrcp(1.0f + vexp2(x * -1.44269504088896340736f));
}
__device__ __forceinline__ float tanh_(float x) {
  return fmaf(2.0f, vrcp(1.0f + vexp2(x * -2.8853900817779268f)), -1.0f);
}

// lgkm-only barrier: LDS visibility without draining global queues.
#define BARRIER() asm volatile("s_waitcnt lgkmcnt(0)\n\ts_barrier" ::: "memory")
#define MFMA __builtin_amdgcn_mfma_f32_16x16x32_bf16

// Planar [16][64] bf16, 16B-chunk XOR swizzle: full-wave b128 = uniform 8 lanes/bank-group.
#define HADDR(row, chunk) (((row) << 6) + ((((chunk) ^ ((row) & 7))) << 3))

__device__ __forceinline__ void unpk(u32x4 p0, u32x4 p1, bf16x8* hi, bf16x8* lo) {
  u32x4 h, l;
  h[0] = __builtin_amdgcn_perm(p0[1], p0[0], 0x05040100u);
  h[1] = __builtin_amdgcn_perm(p0[3], p0[2], 0x05040100u);
  h[2] = __builtin_amdgcn_perm(p1[1], p1[0], 0x05040100u);
  h[3] = __builtin_amdgcn_perm(p1[3], p1[2], 0x05040100u);
  l[0] = __builtin_amdgcn_perm(p0[1], p0[0], 0x07060302u);
  l[1] = __builtin_amdgcn_perm(p0[3], p0[2], 0x07060302u);
  l[2] = __builtin_amdgcn_perm(p1[1], p1[0], 0x07060302u);
  l[3] = __builtin_amdgcn_perm(p1[3], p1[2], 0x07060302u);
  *hi = __builtin_bit_cast(bf16x8, h);
  *lo = __builtin_bit_cast(bf16x8, l);
}

// ---------- Skew-2 pair kernel: 2 layers, register-resident x-seeds ----------
// 512 thr = 8 waves: set = wv>>2 (layer L0+set), 4 waves each.
// Set1 lags set0 by TWO supersteps, so all cross-set data a set needs for its
// NEXT step was written before the PREVIOUS barrier -> x-seed MFMAs run as
// off-chain "tail" work after the epilogue, accumulating into register parity
// xacc[2][4]. Chain per superstep = exactly R9's proven A-chain.
// Superstep n (P = n&1):
//   set0 chain: h0(n)   = ABODY(seed xacc[P]);  reads planes[0][1-P], writes [0][P]
//   set0 tail : xacc[1-P] for t=n+1 from x-queue; refill queue (t=n+3)
//   set1 chain: h1(n-2) = ABODY(seed xacc[P]);  reads planes[1][1-P], writes [1][P]
//               + inline packed global store of h1(n-2)
//   set1 tail : xacc[1-P] for t=n-1 from planes[0][1-P] (h0(n-1), pre-barrier)
// One lgkm barrier per superstep. Numerics = R9 op order (absmax 1.2207e-4).
// In-place (GIN): set0 reads seq[t+3] max, set1 writes seq[n-2] -> gap >=5.
#define SUPERQ(N_, P_)                                                         \
  {                                                                            \
    if (set == 0) {                                                            \
      if ((N_) < T_LEN) {                                                      \
        bf16x8 ahh0 = *(const bf16x8*)&Hhi[0][1 - (P_)][HADDR(nn, cg)];        \
        bf16x8 ahh1 = *(const bf16x8*)&Hhi[0][1 - (P_)][HADDR(nn, 4 + cg)];    \
        bf16x8 ahl0 = *(const bf16x8*)&Hlo[0][1 - (P_)][HADDR(nn, cg)];        \
        bf16x8 ahl1 = *(const bf16x8*)&Hlo[0][1 - (P_)][HADDR(nn, 4 + cg)];    \
        f32x4 accs[4];                                                         \
        _Pragma("unroll") for (int g = 0; g < 4; ++g) {                        \
          f32x4 a = xacc[P_][g];                                               \
          a = MFMA(ahh0, bhh[g][0], a, 0, 0, 0);                               \
          a = MFMA(ahh1, bhh[g][1], a, 0, 0, 0);                               \
          a = MFMA(ahl0, bhh[g][0], a, 0, 0, 0);                               \
          a = MFMA(ahl1, bhh[g][1], a, 0, 0, 0);                               \
          accs[g] = a;                                                         \
        }                                                                      \
        _Pragma("unroll") for (int r = 0; r < 4; ++r) {                        \
          float iv = sigm(accs[0][r]);                                         \
          float fv = sigm(accs[1][r]);                                         \
          float gv = tanh_(accs[2][r]);                                        \
          float ov = sigm(accs[3][r]);                                         \
          cell[r] = fv * cell[r] + iv * gv;                                    \
          float hv = ov * tanh_(cell[r]);                                      \
          __bf16 h1 = (__bf16)hv;                                              \
          __bf16 h2 = (__bf16)(hv - (float)h1);                                \
          int mrow = 4 * cg + r;                                               \
          int ha = HADDR(mrow, uu >> 3) + (uu & 7);                            \
          Hhi[0][P_][ha] = h1;                                                 \
          Hlo[0][P_][ha] = h2;                                                 \
        }                                                                      \
      }                                                                        \
      /* tail: x-seed for t = N_+1 */                                         \
      if ((N_) + 1 < T_LEN) {                                                  \
        if (XIN) {                                                             \
          _Pragma("unroll") for (int g = 0; g < 4; ++g) {                      \
            f32x4 a;                                                           \
            _Pragma("unroll") for (int r = 0; r < 4; ++r)                      \
              a[r] = bias[g] + xw[g*3+0] * xr[P_][r*3+0]                       \
                             + xw[g*3+1] * xr[P_][r*3+1]                       \
                             + xw[g*3+2] * xr[P_][r*3+2];                      \
            xacc[1 - (P_)][g] = a;                                             \
          }                                                                    \
        } else {                                                               \
          bf16x8 xh0, xl0, xh1, xl1;                                           \
          unpk(xpk[P_][0], xpk[P_][1], &xh0, &xl0);                            \
          unpk(xpk[P_][2], xpk[P_][3], &xh1, &xl1);                            \
          _Pragma("unroll") for (int g = 0; g < 4; ++g) {                      \
            f32x4 a = {bias[g], bias[g], bias[g], bias[g]};                    \
            a = MFMA(xh0, bih[g][0], a, 0, 0, 0);                              \
            a = MFMA(xh1, bih[g][1], a, 0, 0, 0);                              \
            a = MFMA(xl0, bih[g][0], a, 0, 0, 0);                              \
            a = MFMA(xl1, bih[g][1], a, 0, 0, 0);                              \
            xacc[1 - (P_)][g] = a;                                             \
          }                                                                    \
        }                                                                      \
      }                                                                        \
      {                                                                        \
        int tp = (N_) + 3; if (tp > T_LEN - 1) tp = T_LEN - 1;                 \
        if (XIN) {                                                             \
          _Pragma("unroll") for (int r = 0; r < 4; ++r)                        \
            _Pragma("unroll") for (int i = 0; i < 3; ++i)                      \
              xr[P_][r*3+i] =                                                  \
                  x_f32[((size_t)(bbase + 4*cg + r) * T_LEN + tp) * 3 + i];    \
        } else {                                                               \
          const unsigned int* px = seqp + xrow + (size_t)tp * HDIM;            \
          xpk[P_][0] = *(const u32x4*)(px + 8 * cg);                           \
          xpk[P_][1] = *(const u32x4*)(px + 8 * cg + 4);                       \
          xpk[P_][2] = *(const u32x4*)(px + 32 + 8 * cg);                      \
          xpk[P_][3] = *(const u32x4*)(px + 32 + 8 * cg + 4);                  \
        }                                                                      \
      }                                                                        \
    } else {                                                                   \
      if ((N_) >= 2) {                                                         \
        const int tl = (N_) - 2;                                               \
        bf16x8 ahh0 = *(const bf16x8*)&Hhi[1][1 - (P_)][HADDR(nn, cg)];        \
        bf16x8 ahh1 = *(const bf16x8*)&Hhi[1][1 - (P_)][HADDR(nn, 4 + cg)];    \
        bf16x8 ahl0 = *(const bf16x8*)&Hlo[1][1 - (P_)][HADDR(nn, cg)];        \
        bf16x8 ahl1 = *(const bf16x8*)&Hlo[1][1 - (P_)][HADDR(nn, 4 + cg)];    \
        f32x4 accs[4];                                                         \
        _Pragma("unroll") for (int g = 0; g < 4; ++g) {                        \
          f32x4 a = xacc[P_][g];                                               \
          a = MFMA(ahh0, bhh[g][0], a, 0, 0, 0);                               \
          a = MFMA(ahh1, bhh[g][1], a, 0, 0, 0);                               \
          a = MFMA(ahl0, bhh[g][0], a, 0, 0, 0);                               \
          a = MFMA(ahl1, bhh[g][1], a, 0, 0, 0);                               \
          accs[g] = a;                                                         \
        }                                                                      \
        _Pragma("unroll") for (int r = 0; r < 4; ++r) {                        \
          float iv = sigm(accs[0][r]);                                         \
          float fv = sigm(accs[1][r]);                                         \
          float gv = tanh_(accs[2][r]);                                        \
          float ov = sigm(accs[3][r]);                                         \
          cell[r] = fv * cell[r] + iv * gv;                                    \
          float hv = ov * tanh_(cell[r]);                                      \
          __bf16 h1 = (__bf16)hv;                                              \
          __bf16 h2 = (__bf16)(hv - (float)h1);                                \
          int mrow = 4 * cg + r;                                               \
          int ha = HADDR(mrow, uu >> 3) + (uu & 7);                            \
          Hhi[1][P_][ha] = h1;                                                 \
          Hlo[1][P_][ha] = h2;                                                 \
          unsigned int hb = (unsigned int)__builtin_bit_cast(unsigned short, h1) \
                          | ((unsigned int)__builtin_bit_cast(unsigned short, h2) << 16); \
          seqp[((size_t)(bbase + mrow) * T_LEN + tl) * HDIM + uu] = hb;        \
        }                                                                      \
      }                                                                        \
      /* tail: x-seed for t = N_-1 from upstream h0(N_-1), written pre-barrier */ \
      if ((N_) >= 1 && (N_) - 1 < T_LEN) {                                     \
        bf16x8 xh0 = *(const bf16x8*)&Hhi[0][1 - (P_)][HADDR(nn, cg)];         \
        bf16x8 xh1 = *(const bf16x8*)&Hhi[0][1 - (P_)][HADDR(nn, 4 + cg)];     \
        bf16x8 xl0 = *(const bf16x8*)&Hlo[0][1 - (P_)][HADDR(nn, cg)];         \
        bf16x8 xl1 = *(const bf16x8*)&Hlo[0][1 - (P_)][HADDR(nn, 4 + cg)];     \
        _Pragma("unroll") for (int g = 0; g < 4; ++g) {                        \
          f32x4 a = {bias[g], bias[g], bias[g], bias[g]};                      \
          a = MFMA(xh0, bih[g][0], a, 0, 0, 0);                                \
          a = MFMA(xh1, bih[g][1], a, 0, 0, 0);                                \
          a = MFMA(xl0, bih[g][0], a, 0, 0, 0);                                \
          a = MFMA(xl1, bih[g][1], a, 0, 0, 0);                                \
          xacc[1 - (P_)][g] = a;                                               \
        }                                                                      \
      }                                                                        \
    }                                                                          \
    BARRIER();                                                                 \
  }

template<int L0, bool XIN>
__global__ __launch_bounds__(512, 2)
void lstm_pairq(const float* __restrict__ x_f32,
                const float* __restrict__ w_ih0,
                const float* __restrict__ w_ih_rest,
                const float* __restrict__ w_hh,
                const float* __restrict__ b_ih,
                const float* __restrict__ b_hh,
                unsigned int* __restrict__ seqp)
{
  const int tid  = threadIdx.x;
  const int lane = tid & 63;
  const int wv   = tid >> 6;
  const int set  = wv >> 2;       // 0,1 (wave-uniform)
  const int wq   = wv & 3;
  const int nn   = lane & 15;
  const int cg   = lane >> 4;
  const int bbase = blockIdx.x * 16;
  const int grow = 16 * wq + nn;
  const int uu   = grow;
  const int layer = L0 + set;

  __shared__ __align__(16) __bf16 Hhi[2][2][1024];  // 8 KB
  __shared__ __align__(16) __bf16 Hlo[2][2][1024];  // 8 KB

  bf16x8 bhh[4][2];
#pragma unroll
  for (int g = 0; g < 4; ++g)
#pragma unroll
    for (int kk = 0; kk < 2; ++kk) {
      const float* wp = w_hh + (size_t)layer * 256 * 64
                      + (size_t)(64 * g + grow) * 64 + kk * 32 + 8 * cg;
      bf16x8 t;
#pragma unroll
      for (int e = 0; e < 8; ++e) t[e] = (__bf16)wp[e];
      bhh[g][kk] = t;
    }
  bf16x8 bih[4][2];
  float xw[12];
  if (XIN && set == 0) {
#pragma unroll
    for (int g = 0; g < 4; ++g)
#pragma unroll
      for (int i = 0; i < 3; ++i) xw[g * 3 + i] = w_ih0[(64 * g + grow) * 3 + i];
  } else {
    const float* wih_l = w_ih_rest + (size_t)(layer - 1) * 256 * 64;
#pragma unroll
    for (int g = 0; g < 4; ++g)
#pragma unroll
      for (int kk = 0; kk < 2; ++kk) {
        const float* wp = wih_l + (size_t)(64 * g + grow) * 64 + kk * 32 + 8 * cg;
        bf16x8 t;
#pragma unroll
        for (int e = 0; e < 8; ++e) t[e] = (__bf16)wp[e];
        bih[g][kk] = t;
      }
  }
  float bias[4];
#pragma unroll
  for (int g = 0; g < 4; ++g) {
    int row = layer * 256 + 64 * g + grow;
    bias[g] = b_ih[row] + b_hh[row];
  }

  for (int q = tid; q < 4 * 1024; q += 512) {
    ((__bf16*)Hhi)[q] = (__bf16)0.f;
    ((__bf16*)Hlo)[q] = (__bf16)0.f;
  }

  float cell[4] = {0.f, 0.f, 0.f, 0.f};
  const size_t xrow = (size_t)(bbase + nn) * T_LEN * HDIM;

  f32x4 xacc[2][4];   // register x-seed, parity-indexed (macro-literal P_ only)
  float xr[2][12];    // set0 XIN queue: xr[p] holds x(t) for t = next odd/even
  u32x4 xpk[2][4];    // set0 GIN queue

  if (set == 0) {
    if (XIN) {
      float x0[12];
#pragma unroll
      for (int r = 0; r < 4; ++r)
#pragma unroll
        for (int i = 0; i < 3; ++i)
          x0[r*3+i] = x_f32[((size_t)(bbase + 4*cg + r) * T_LEN + 0) * 3 + i];
#pragma unroll
      for (int g = 0; g < 4; ++g) {
        f32x4 a;
#pragma unroll
        for (int r = 0; r < 4; ++r)
          a[r] = bias[g] + xw[g*3+0]*x0[r*3+0] + xw[g*3+1]*x0[r*3+1] + xw[g*3+2]*x0[r*3+2];
        xacc[0][g] = a;
      }
      // xr[0] = x(1), xr[1] = x(2)  (consumed at supersteps 0,1 for t=1,2)
#pragma unroll
      for (int p = 0; p < 2; ++p)
#pragma unroll
        for (int r = 0; r < 4; ++r)
#pragma unroll
          for (int i = 0; i < 3; ++i)
            xr[p][r*3+i] = x_f32[((size_t)(bbase + 4*cg + r) * T_LEN + (p + 1)) * 3 + i];
    } else {
      const unsigned int* px = seqp + xrow;
      u32x4 q0 = *(const u32x4*)(px + 8 * cg);
      u32x4 q1 = *(const u32x4*)(px + 8 * cg + 4);
      u32x4 q2 = *(const u32x4*)(px + 32 + 8 * cg);
      u32x4 q3 = *(const u32x4*)(px + 32 + 8 * cg + 4);
      bf16x8 xh0, xl0, xh1, xl1;
      unpk(q0, q1, &xh0, &xl0);
      unpk(q2, q3, &xh1, &xl1);
#pragma unroll
      for (int g = 0; g < 4; ++g) {
        f32x4 a = {bias[g], bias[g], bias[g], bias[g]};
        a = MFMA(xh0, bih[g][0], a, 0, 0, 0);
        a = MFMA(xh1, bih[g][1], a, 0, 0, 0);
        a = MFMA(xl0, bih[g][0], a, 0, 0, 0);
        a = MFMA(xl1, bih[g][1], a, 0, 0, 0);
        xacc[0][g] = a;
      }
      // xpk[0] = seq(1), xpk[1] = seq(2)
#pragma unroll
      for (int p = 0; p < 2; ++p) {
        const unsigned int* pq = seqp + xrow + (size_t)(p + 1) * HDIM;
        xpk[p][0] = *(const u32x4*)(pq + 8 * cg);
        xpk[p][1] = *(const u32x4*)(pq + 8 * cg + 4);
        xpk[p][2] = *(const u32x4*)(pq + 32 + 8 * cg);
        xpk[p][3] = *(const u32x4*)(pq + 32 + 8 * cg + 4);
      }
    }
  }
  __syncthreads();

  for (int n = 0; n < NSUP; n += 2) {
    SUPERQ(n,     0);
    SUPERQ(n + 1, 1);
  }
}

// -------------- Single-layer kernel (R9/R11-proven, layer 4) ---------------
#define STEP(T0, P)                                                            \
  {                                                                            \
    if (isA) {                                                                 \
      bf16x8 ahh0 = *(const bf16x8*)&h_hi[P][HADDR(nn, cg)];                   \
      bf16x8 ahh1 = *(const bf16x8*)&h_hi[P][HADDR(nn, 4 + cg)];               \
      bf16x8 ahl0 = *(const bf16x8*)&h_lo[P][HADDR(nn, cg)];                   \
      bf16x8 ahl1 = *(const bf16x8*)&h_lo[P][HADDR(nn, 4 + cg)];               \
      f32x4 accs[4];                                                           \
      _Pragma("unroll")                                                        \
      for (int g = 0; g < 4; ++g) {                                            \
        f32x4 a = accx[P][g][wq * 64 + lane];                                  \
        a = MFMA(ahh0, bhh[g][0], a, 0, 0, 0);                                 \
        a = MFMA(ahh1, bhh[g][1], a, 0, 0, 0);                                 \
        a = MFMA(ahl0, bhh[g][0], a, 0, 0, 0);                                 \
        a = MFMA(ahl1, bhh[g][1], a, 0, 0, 0);                                 \
        accs[g] = a;                                                           \
      }                                                                        \
      _Pragma("unroll")                                                        \
      for (int r = 0; r < 4; ++r) {                                            \
        float iv = sigm(accs[0][r]);                                           \
        float fv = sigm(accs[1][r]);                                           \
        float gv = tanh_(accs[2][r]);                                          \
        float ov = sigm(accs[3][r]);                                           \
        cell[r] = fv * cell[r] + iv * gv;                                      \
        float hv = ov * tanh_(cell[r]);                                        \
        __bf16 h1 = (__bf16)hv;                                                \
        __bf16 h2 = (__bf16)(hv - (float)h1);                                  \
        int mrow = 4 * cg + r;                                                 \
        int ha = HADDR(mrow, uu >> 3) + (uu & 7);                              \
        h_hi[1 - (P)][ha] = h1;                                                \
        h_lo[1 - (P)][ha] = h2;                                                \
      }                                                                        \
    } else {                                                                   \
      if ((T0) > 0) {                                                          \
        _Pragma("unroll")                                                      \
        for (int r = 0; r < 4; ++r) {                                          \
          int mrow = 4 * cg + r;                                               \
          int ha = HADDR(mrow, uu >> 3) + (uu & 7);                            \
          unsigned int hb =                                                    \
              (unsigned int)__builtin_bit_cast(unsigned short, h_hi[P][ha])    \
            | ((unsigned int)__builtin_bit_cast(unsigned short, h_lo[P][ha]) << 16); \
          seqp[((size_t)(bbase + mrow) * T_LEN + (T0) - 1) * HDIM + uu] = hb;  \
        }                                                                      \
      }                                                                        \
      if ((T0) + 1 < T_LEN) {                                                  \
        bf16x8 xh0, xl0, xh1, xl1;                                             \
        unpk(xpk[P][0], xpk[P][1], &xh0, &xl0);                                \
        unpk(xpk[P][2], xpk[P][3], &xh1, &xl1);                                \
        _Pragma("unroll")                                                      \
        for (int g = 0; g < 4; ++g) {                                          \
          f32x4 a = {bias[g], bias[g], bias[g], bias[g]};                      \
          a = MFMA(xh0, bih[g][0], a, 0, 0, 0);                                \
          a = MFMA(xh1, bih[g][1], a, 0, 0, 0);                                \
          a = MFMA(xl0, bih[g][0], a, 0, 0, 0);                                \
          a = MFMA(xl1, bih[g][1], a, 0, 0, 0);                                \
          accx[1 - (P)][g][wq * 64 + lane] = a;                                \
        }                                                                      \
      }                                                                        \
      {                                                                        \
        int tp = (T0) + 3; if (tp >= T_LEN) tp = T_LEN - 1;                    \
        const unsigned int* px = seqp + xrow + (size_t)tp * HDIM;              \
        xpk[P][0] = *(const u32x4*)(px + 8 * cg);                              \
        xpk[P][1] = *(const u32x4*)(px + 8 * cg + 4);                          \
        xpk[P][2] = *(const u32x4*)(px + 32 + 8 * cg);                         \
        xpk[P][3] = *(const u32x4*)(px + 32 + 8 * cg + 4);                     \
      }                                                                        \
    }                                                                          \
    BARRIER();                                                                 \
  }

__global__ __launch_bounds__(512, 2)
void lstm_single(const float* __restrict__ w_ih,
                 const float* __restrict__ w_hh,
                 const float* __restrict__ b_ih,
                 const float* __restrict__ b_hh,
                 unsigned int* seqp)
{
    const int tid  = threadIdx.x;
    const int lane = tid & 63;
    const int wv   = tid >> 6;
    const bool isA = (wv < 4);
    const int wq   = wv & 3;
    const int nn   = lane & 15;
    const int cg   = lane >> 4;
    const int bbase = blockIdx.x * 16;
    const int grow = 16 * wq + nn;
    const int uu   = grow;

    __shared__ __align__(16) __bf16 h_hi[2][16 * 64];
    __shared__ __align__(16) __bf16 h_lo[2][16 * 64];
    __shared__ __align__(16) f32x4 accx[2][4][256];

    bf16x8 bhh[4][2];
    bf16x8 bih[4][2];
    float bias[4];
    if (isA) {
#pragma unroll
      for (int g = 0; g < 4; ++g)
#pragma unroll
        for (int kk = 0; kk < 2; ++kk) {
          const float* wp = w_hh + (size_t)(64 * g + grow) * 64 + kk * 32 + 8 * cg;
          bf16x8 t;
#pragma unroll
          for (int e = 0; e < 8; ++e) t[e] = (__bf16)wp[e];
          bhh[g][kk] = t;
        }
    } else {
#pragma unroll
      for (int g = 0; g < 4; ++g) {
        int row = 64 * g + grow;
        bias[g] = b_ih[row] + b_hh[row];
      }
#pragma unroll
      for (int g = 0; g < 4; ++g)
#pragma unroll
        for (int kk = 0; kk < 2; ++kk) {
          const float* wp = w_ih + (size_t)(64 * g + grow) * 64 + kk * 32 + 8 * cg;
          bf16x8 t;
#pragma unroll
          for (int e = 0; e < 8; ++e) t[e] = (__bf16)wp[e];
          bih[g][kk] = t;
        }
    }

    for (int q = tid; q < 1024; q += 512) {
      h_hi[0][q] = (__bf16)0.f; h_hi[1][q] = (__bf16)0.f;
      h_lo[0][q] = (__bf16)0.f; h_lo[1][q] = (__bf16)0.f;
    }

    float cell[4] = {0.f, 0.f, 0.f, 0.f};
    const size_t xrow = (size_t)(bbase + nn) * T_LEN * HDIM;
    u32x4 xpk[2][4];

    if (!isA) {
      const unsigned int* px = seqp + xrow;
      u32x4 q0 = *(const u32x4*)(px + 8 * cg);
      u32x4 q1 = *(const u32x4*)(px + 8 * cg + 4);
      u32x4 q2 = *(const u32x4*)(px + 32 + 8 * cg);
      u32x4 q3 = *(const u32x4*)(px + 32 + 8 * cg + 4);
      bf16x8 xh0, xl0, xh1, xl1;
      unpk(q0, q1, &xh0, &xl0);
      unpk(q2, q3, &xh1, &xl1);
#pragma unroll
      for (int g = 0; g < 4; ++g) {
        f32x4 a = {bias[g], bias[g], bias[g], bias[g]};
        a = MFMA(xh0, bih[g][0], a, 0, 0, 0);
        a = MFMA(xh1, bih[g][1], a, 0, 0, 0);
        a = MFMA(xl0, bih[g][0], a, 0, 0, 0);
        a = MFMA(xl1, bih[g][1], a, 0, 0, 0);
        accx[0][g][wq * 64 + lane] = a;
      }
#pragma unroll
      for (int p = 0; p < 2; ++p) {
        const unsigned int* pq = seqp + xrow + (size_t)(p + 1) * HDIM;
        xpk[p][0] = *(const u32x4*)(pq + 8 * cg);
        xpk[p][1] = *(const u32x4*)(pq + 8 * cg + 4);
        xpk[p][2] = *(const u32x4*)(pq + 32 + 8 * cg);
        xpk[p][3] = *(const u32x4*)(pq + 32 + 8 * cg + 4);
      }
    }
    __syncthreads();

    if (isA) __builtin_amdgcn_s_setprio(1);
    for (int t = 0; t < T_LEN; t += 2) {
      STEP(t, 0);
      STEP(t + 1, 1);
    }
    if (isA) __builtin_amdgcn_s_setprio(0);

    if (!isA) {
#pragma unroll
      for (int r = 0; r < 4; ++r) {
        int mrow = 4 * cg + r;
        int ha = HADDR(mrow, uu >> 3) + (uu & 7);
        unsigned int hb =
            (unsigned int)__builtin_bit_cast(unsigned short, h_hi[0][ha])
          | ((unsigned int)__builtin_bit_cast(unsigned short, h_lo[0][ha]) << 16);
        seqp[((size_t)(bbase + mrow) * T_LEN + (T_LEN - 1)) * HDIM + uu] = hb;
      }
    }
}

// FC head: out[b] = fc2_b + fc2_w . relu(fc1_b + fc1_w . h_T[b])
__global__ __launch_bounds__(256, 1)
void fc_head(const unsigned int* __restrict__ seqp,
             const float* __restrict__ fc1_w, const float* __restrict__ fc1_b,
             const float* __restrict__ fc2_w, const float* __restrict__ fc2_b,
             float* __restrict__ out)
{
    __shared__ float w1[FC1 * HDIM];
    __shared__ float b1[FC1];
    __shared__ float w2[FC1];
    const int tid = threadIdx.x;
    for (int i = tid; i < FC1 * HDIM; i += 256) w1[i] = fc1_w[i];
    if (tid < FC1) { b1[tid] = fc1_b[tid]; w2[tid] = fc2_w[tid]; }
    __syncthreads();

    const int b = blockIdx.x * 256 + tid;
    const size_t base = ((size_t)b * T_LEN + (T_LEN - 1)) * HDIM;
    float h[HDIM];
#pragma unroll
    for (int q = 0; q < HDIM; ++q) {
      unsigned int v = seqp[base + q];
      float hi = (float)__builtin_bit_cast(__bf16, (unsigned short)(v & 0xffffu));
      float lo = (float)__builtin_bit_cast(__bf16, (unsigned short)(v >> 16));
      h[q] = hi + lo;
    }
    float acc2 = fc2_b[0];
    for (int m = 0; m < FC1; ++m) {
      float a = b1[m];
#pragma unroll
      for (int q = 0; q < HDIM; ++q) a += w1[m * HDIM + q] * h[q];
      acc2 += w2[m] * fmaxf(a, 0.0f);
    }
    out[b] = acc2;
}

extern "C" void kernel_launch(void* const* d_in, const int* in_sizes, int n_in,
                              void* d_out, int out_size, void* d_ws, size_t ws_size,
                              hipStream_t stream) {
    const float* x         = (const float*)d_in[0];
    const float* w_ih0     = (const float*)d_in[1];
    const float* w_ih_rest = (const float*)d_in[2];
    const float* w_hh      = (const float*)d_in[3];
    const float* b_ih      = (const float*)d_in[4];
    const float* b_hh      = (const float*)d_in[5];
    const float* fc1_w     = (const float*)d_in[6];
    const float* fc1_b     = (const float*)d_in[7];
    const float* fc2_w     = (const float*)d_in[8];
    const float* fc2_b     = (const float*)d_in[9];
    float* out = (float*)d_out;

    unsigned int* seqp = (unsigned int*)d_ws;   // [B,T,64] packed = 256 MiB

    // layers 0+1, skew-2 pair; writes seq1
    lstm_pairq<0, true><<<dim3(B_TOT / 16), dim3(512), 0, stream>>>(
        x, w_ih0, w_ih_rest, w_hh, b_ih, b_hh, seqp);
    // layers 2+3, skew-2 pair; reads seq1 / writes seq3 in-place (gap >= 5)
    lstm_pairq<2, false><<<dim3(B_TOT / 16), dim3(512), 0, stream>>>(
        x, w_ih0, w_ih_rest, w_hh, b_ih, b_hh, seqp);
    // layer 4; reads seq3 / writes seq4 in-place (gap 4)
    lstm_single<<<dim3(B_TOT / 16), dim3(512), 0, stream>>>(
        w_ih_rest + (size_t)3 * 256 * HDIM,
        w_hh + (size_t)4 * 256 * HDIM,
        b_ih + (size_t)4 * 256,
        b_hh + (size_t)4 * 256,
        seqp);
    fc_head<<<dim3(B_TOT / 256), dim3(256), 0, stream>>>(
        seqp, fc1_w, fc1_b, fc2_w, fc2_b, out);
}